// Round 1
// baseline (189.592 us; speedup 1.0000x reference)
//
#include <hip/hip_runtime.h>

// RegionSelector: sampling_map [B,1,512,512] f32 -> [B,1,2] int32 (row,col) of
// argmax over 2x2 sliding-window sums of 4x4 grid-cell means.
// GRID=4, WIN=3, TOPK=1, H=W=512 -> grid cell = 128x128, n = 2.

#define H 512
#define W 512
#define ROWS_PER_BLOCK 32
#define BLOCKS_PER_BATCH 16  // 512 / 32

// Kernel 1: per-block partial sums of 4 grid-column strips over 32 rows.
// Block bid = b*16 + rb covers rows [rb*32, rb*32+32) of batch b.
// Writes partial[bid*4 + gc] (gc = grid column 0..3).
__global__ __launch_bounds__(256) void grid_strip_sum(
    const float* __restrict__ src, float* __restrict__ partial) {
  const int bid = blockIdx.x;
  const int b = bid >> 4;
  const int rb = bid & 15;
  const int t = threadIdx.x;

  // float4 view of this block's 32x512 tile: 32 rows * 128 float4/row = 4096.
  const float4* base = (const float4*)(src + (size_t)b * (H * W) +
                                       (size_t)rb * ROWS_PER_BLOCK * W);
  // f = t + 256*k; col4 = f & 127 = t & 127 (constant per thread), so each
  // thread's grid column gc = (t & 127) >> 5 is fixed -> one scalar acc.
  float acc = 0.0f;
#pragma unroll
  for (int k = 0; k < 16; ++k) {
    float4 v = base[t + 256 * k];
    acc += (v.x + v.y) + (v.z + v.w);
  }

  __shared__ float lds[256];
  lds[t] = acc;
  __syncthreads();
  // Fold 256 -> 128: entry e (0..127) now corresponds to col4 = e, gc = e>>5.
  if (t < 128) lds[t] += lds[t + 128];
  __syncthreads();
  // Tree-reduce each 32-entry group (one per grid column).
#pragma unroll
  for (int off = 16; off > 0; off >>= 1) {
    if (t < 128 && (t & 31) < off) lds[t] += lds[t + off];
    __syncthreads();
  }
  if (t < 4) partial[bid * 4 + t] = lds[t * 32];
}

// Kernel 2: one thread per batch. Combine 16 blocks x 4 cols of partials into
// the 4x4 cell-sum matrix, compute the four 3x3 window sums, argmax.
__global__ __launch_bounds__(128) void select_region(
    const float* __restrict__ partial, int* __restrict__ out, int B) {
  const int b = blockIdx.x * blockDim.x + threadIdx.x;
  if (b >= B) return;
  const float* p = partial + (size_t)b * (BLOCKS_PER_BATCH * 4);

  float S[4][4];
#pragma unroll
  for (int gr = 0; gr < 4; ++gr) {
#pragma unroll
    for (int gc = 0; gc < 4; ++gc) {
      float s = 0.0f;
#pragma unroll
      for (int j = 0; j < 4; ++j) s += p[(gr * 4 + j) * 4 + gc];
      S[gr][gc] = s;
    }
  }

  // Window sums over 3x3, n=2. Scan in row-major index order; strict '>'
  // keeps the lowest index on ties (matches jax.lax.top_k).
  float best = -__builtin_inff();
  int bi = 0;
#pragma unroll
  for (int i = 0; i < 2; ++i) {
#pragma unroll
    for (int j = 0; j < 2; ++j) {
      float ws = 0.0f;
#pragma unroll
      for (int di = 0; di < 3; ++di)
#pragma unroll
        for (int dj = 0; dj < 3; ++dj) ws += S[i + di][j + dj];
      const int idx = i * 2 + j;
      if (ws > best) {
        best = ws;
        bi = idx;
      }
    }
  }
  out[b * 2 + 0] = bi >> 1;  // row = idx / n
  out[b * 2 + 1] = bi & 1;   // col = idx % n
}

extern "C" void kernel_launch(void* const* d_in, const int* in_sizes, int n_in,
                              void* d_out, int out_size, void* d_ws,
                              size_t ws_size, hipStream_t stream) {
  const float* src = (const float*)d_in[0];
  int* out = (int*)d_out;
  float* partial = (float*)d_ws;  // B*16*4 floats = 32 KB for B=128

  const int B = in_sizes[0] / (H * W);

  grid_strip_sum<<<B * BLOCKS_PER_BATCH, 256, 0, stream>>>(src, partial);
  select_region<<<(B + 127) / 128, 128, 0, stream>>>(partial, out, B);
}